// Round 1
// 143.283 us; speedup vs baseline: 1.0086x; 1.0086x over previous
//
#include <hip/hip_runtime.h>
#include <math.h>

#define Bn 8
#define Hn 128
#define Pn 128
#define Ln 4096
#define LF 2049           // Ln/2 + 1
#define NROWS (Bn*Hn)     // 1024
#define NT 32             // frequency columns per mixmm block
#define NTILES 65         // ceil(2049/32) per batch
#define PLSZ 4096         // halfs per data plane (32 x 128)
#define WPLSZ 16384       // halfs per weight plane (128 x 128)
#define TSCALE 64.0f      // T stored as T/64 (fp16 range guard); W2 pre-scaled x64

// LDS skew for FFT buffers: +1 float2 every 16 -> strided Stockham writes <=2-way
#define SKEW(a) ((a) + ((a) >> 4))
#define FBUF 2176          // SKEW(2047)+1 rounded up

typedef _Float16 f16x8 __attribute__((ext_vector_type(8)));
typedef float f32x4 __attribute__((ext_vector_type(4)));

// Fast HW sin/cos: __sinf/__cosf lower to the native v_sin_f32/v_cos_f32 path.
__device__ __forceinline__ void fsincos(float a, float* s, float* c) {
    *s = __sinf(a);
    *c = __cosf(a);
}

__device__ __forceinline__ float2 cmulff(float2 a, float2 b) {
    return make_float2(a.x * b.x - a.y * b.y, a.x * b.y + a.y * b.x);
}

// ---------------------------------------------------------------------------
// prep: fold H-axis FFTs into weights; fp16 planes {0:r, 1:i},
// [m][k] row-major 128x128.
//   W1[p][h] = (B_bar @ F)[p][h]               (stage 1: T = B2 @ U)
//   W2[h][p] = (Finv @ C)[h][p] * TSCALE       (stage 2: C2 @ T, T stored /64)
//   E [a][q] = (D @ F)[a][q]  (fp32 temp)
//   W3[h][q] = (Finv @ E)[h][q]                (stage 2: D2 @ U)
//
// r8: per-iteration fsincos replaced by a chained unit rotation
// (1 fsincos/thread + 4 FLOP/element, 2 independent chains for ILP).
// ---------------------------------------------------------------------------
__device__ __forceinline__ void write2(_Float16* __restrict__ W, int idx,
                                       float vr, float vi) {
    W[0 * WPLSZ + idx] = (_Float16)vr;
    W[1 * WPLSZ + idx] = (_Float16)vi;
}

// sum_{q=0}^{127} (src[q*stride] + i src[q*stride+1]) * exp(i*ang*q)
// stride in floats. Two interleaved chains (even/odd q) for ILP.
__device__ __forceinline__ void dftsum(const float* __restrict__ src, int stride,
                                       float ang, float& outr, float& outi) {
    float stepi, stepr;
    fsincos(ang, &stepi, &stepr);
    float s2r = stepr * stepr - stepi * stepi;
    float s2i = 2.0f * stepr * stepi;
    float w0r = 1.0f, w0i = 0.0f;          // even q chain
    float w1r = stepr, w1i = stepi;        // odd q chain
    float sr = 0.f, si = 0.f, tr = 0.f, ti = 0.f;
    #pragma unroll 4
    for (int q = 0; q < 128; q += 2) {
        float ar = src[q * stride], ai = src[q * stride + 1];
        sr += ar * w0r - ai * w0i;
        si += ar * w0i + ai * w0r;
        float n0 = w0r * s2r - w0i * s2i;
        w0i = w0r * s2i + w0i * s2r;
        w0r = n0;
        float br = src[(q + 1) * stride], bi = src[(q + 1) * stride + 1];
        tr += br * w1r - bi * w1i;
        ti += br * w1i + bi * w1r;
        float n1 = w1r * s2r - w1i * s2i;
        w1i = w1r * s2i + w1i * s2r;
        w1r = n1;
    }
    outr = sr + tr;
    outi = si + ti;
}

__global__ void prep_ABE_k(const float* __restrict__ B_ri, const float* __restrict__ C_ri,
                           const float* __restrict__ D_ri,
                           _Float16* __restrict__ W1, _Float16* __restrict__ W2,
                           float2* __restrict__ E) {
    int bid = blockIdx.x;
    int idx = (bid & 63) * 256 + threadIdx.x;   // 0..16383
    int rrow = idx >> 7, ccol = idx & 127;
    if (bid < 64) {
        // W1[p][h] = sum_q B[rrow][q] * exp(-i*pi*q*ccol/64)
        float sr, si;
        dftsum(B_ri + rrow * 256, 2, -3.14159265358979f * (float)ccol / 64.0f, sr, si);
        write2(W1, idx, sr, si);
    } else if (bid < 128) {
        // W2[h][p] = sum_h2 C[h2][ccol] * exp(+i*pi*rrow*h2/64), x TSCALE/128
        float sr, si;
        dftsum(C_ri + ccol * 2, 256, 3.14159265358979f * (float)rrow / 64.0f, sr, si);
        write2(W2, idx, sr * (TSCALE / 128.0f), si * (TSCALE / 128.0f));
    } else {
        // E[a][q] = sum_c D[rrow][c] * exp(-i*pi*c*ccol/64)
        float sr, si;
        dftsum(D_ri + rrow * 256, 2, -3.14159265358979f * (float)ccol / 64.0f, sr, si);
        E[idx] = make_float2(sr, si);
    }
}

__global__ void prep_W3_k(const float2* __restrict__ E, _Float16* __restrict__ W3) {
    int idx = blockIdx.x * blockDim.x + threadIdx.x;   // h*128 + q
    int h = idx >> 7, q = idx & 127;
    // W3[h][q] = (1/128) sum_a E[a][q] * exp(+i*pi*h*a/64)
    float sr, si;
    dftsum((const float*)E + q * 2, 256, 3.14159265358979f * (float)h / 64.0f, sr, si);
    write2(W3, idx, sr * (1.0f / 128.0f), si * (1.0f / 128.0f));
}

// ---------------------------------------------------------------------------
// 2048-pt Stockham FFT in LDS: radix-8 x3 + radix-4 (final, twiddle-free).
// r8: IN-PLACE single buffer (read-all -> barrier -> write-all) so LDS/block
// halves (34.8 -> 17.4 KB) -> 6 blocks/CU. Twiddles: one fsincos per stage,
// w^2..w^7 by a depth-3 complex-mult tree (replaces 7 fsincos pairs).
// ---------------------------------------------------------------------------
__device__ __forceinline__ float2 cadd2(float2 a, float2 b) { return make_float2(a.x + b.x, a.y + b.y); }
__device__ __forceinline__ float2 csub2(float2 a, float2 b) { return make_float2(a.x - b.x, a.y - b.y); }

template <int SIGN>
__device__ __forceinline__ void dft4(float2 a0, float2 a1, float2 a2, float2 a3,
                                     float2& y0, float2& y1, float2& y2, float2& y3) {
    float t0x = a0.x + a2.x, t0y = a0.y + a2.y;
    float t1x = a0.x - a2.x, t1y = a0.y - a2.y;
    float t2x = a1.x + a3.x, t2y = a1.y + a3.y;
    float t3x = a1.x - a3.x, t3y = a1.y - a3.y;
    y0 = make_float2(t0x + t2x, t0y + t2y);
    y2 = make_float2(t0x - t2x, t0y - t2y);
    y1 = make_float2(t1x - (float)SIGN * t3y, t1y + (float)SIGN * t3x);
    y3 = make_float2(t1x + (float)SIGN * t3y, t1y - (float)SIGN * t3x);
}

template <int SIGN>
__device__ __forceinline__ void fft2048_ip(float2* buf) {
    const int tid = threadIdx.x;
    #pragma unroll
    for (int stg = 0; stg < 3; ++stg) {
        const int ls = 3 * stg;           // s = 8^stg
        const int q = tid & ((1 << ls) - 1);
        const int p = tid >> ls;
        float2 a[8];
        #pragma unroll
        for (int u = 0; u < 8; ++u) a[u] = buf[SKEW(tid + (u << 8))];
        __syncthreads();                  // all reads done before any write
        float2 A0, A1, A2, A3, B0, B1, B2, B3;
        dft4<SIGN>(a[0], a[2], a[4], a[6], A0, A1, A2, A3);
        dft4<SIGN>(a[1], a[3], a[5], a[7], B0, B1, B2, B3);
        const float c45 = 0.70710678118655f;
        float2 w1v = make_float2(c45 * (B1.x - (float)SIGN * B1.y), c45 * ((float)SIGN * B1.x + B1.y));
        float2 w2v = make_float2(-(float)SIGN * B2.y, (float)SIGN * B2.x);
        float2 w3v = make_float2(c45 * (-B3.x - (float)SIGN * B3.y), c45 * ((float)SIGN * B3.x - B3.y));
        float2 b[8];
        b[0] = cadd2(A0, B0);  b[4] = csub2(A0, B0);
        b[1] = cadd2(A1, w1v); b[5] = csub2(A1, w1v);
        b[2] = cadd2(A2, w2v); b[6] = csub2(A2, w2v);
        b[3] = cadd2(A3, w3v); b[7] = csub2(A3, w3v);
        // twiddle j*ang via tree: 1 fsincos + 6 cmul (depth 3)
        float ang = (float)SIGN * 6.28318530717959f * (float)p * (1.0f / (float)(2048 >> ls));
        float st, ct; fsincos(ang, &st, &ct);
        float2 T1 = make_float2(ct, st);
        float2 T2 = cmulff(T1, T1);
        float2 T3 = cmulff(T2, T1);
        float2 T4 = cmulff(T2, T2);
        float2 T5 = cmulff(T4, T1);
        float2 T6 = cmulff(T4, T2);
        float2 T7 = cmulff(T4, T3);
        b[1] = cmulff(b[1], T1);
        b[2] = cmulff(b[2], T2);
        b[3] = cmulff(b[3], T3);
        b[4] = cmulff(b[4], T4);
        b[5] = cmulff(b[5], T5);
        b[6] = cmulff(b[6], T6);
        b[7] = cmulff(b[7], T7);
        const int base = q + (p << (ls + 3));
        #pragma unroll
        for (int j = 0; j < 8; ++j) buf[SKEW(base + (j << ls))] = b[j];
        __syncthreads();
    }
    // final radix-4: s=512, m=1 -> p=0, twiddles = 1.
    // Per-thread butterflies read and write the SAME 4 slots -> in-place safe
    // without an extra barrier.
    #pragma unroll
    for (int r = 0; r < 2; ++r) {
        int k = tid + (r << 8);
        float2 a0 = buf[SKEW(k)];
        float2 a1 = buf[SKEW(k + 512)];
        float2 a2 = buf[SKEW(k + 1024)];
        float2 a3 = buf[SKEW(k + 1536)];
        float2 y0, y1, y2, y3;
        dft4<SIGN>(a0, a1, a2, a3, y0, y1, y2, y3);
        buf[SKEW(k)] = y0;
        buf[SKEW(k + 512)] = y1;
        buf[SKEW(k + 1024)] = y2;
        buf[SKEW(k + 1536)] = y3;
    }
    __syncthreads();
}

// rfft via real-packing: z[n] = u[2n] + i u[2n+1]; U from Z by even/odd unpack.
// Unpack rotation exp(-i*pi*l/2048) chained across the strided loop
// (constant step exp(-i*pi/8)).
__global__ __launch_bounds__(256, 6) void rfft_rows_k(const float* __restrict__ u,
                                                      float2* __restrict__ Uhat) {
    __shared__ __align__(16) float2 buf[FBUF];
    const int row = blockIdx.x;
    const int tid = threadIdx.x;
    const float4* up4 = (const float4*)(u + (size_t)row * Ln);
    #pragma unroll
    for (int r = 0; r < 4; ++r) {
        float4 v = up4[tid + (r << 8)];
        int i = 2 * (tid + (r << 8));
        buf[SKEW(i)] = make_float2(v.x, v.y);
        buf[SKEW(i + 1)] = make_float2(v.z, v.w);
    }
    __syncthreads();
    fft2048_ip<-1>(buf);
    float2* op = Uhat + (size_t)row * LF;
    float s, c;
    fsincos(-3.14159265358979f * (float)tid / 2048.0f, &s, &c);
    const float c8 = 0.92387953251129f, s8 = -0.38268343236509f;  // exp(-i*pi/8)
    for (int l = tid; l < 1025; l += 256) {
        float2 Zl = buf[SKEW(l)];
        float2 Zm = buf[SKEW((2048 - l) & 2047)];
        float2 Fe = make_float2(0.5f * (Zl.x + Zm.x), 0.5f * (Zl.y - Zm.y));
        float2 Dv = make_float2(0.5f * (Zl.x - Zm.x), 0.5f * (Zl.y + Zm.y));
        float2 Fo = make_float2(Dv.y, -Dv.x);                 // Dv / i
        float2 TF = make_float2(Fo.x * c - Fo.y * s, Fo.x * s + Fo.y * c);
        op[l] = make_float2(Fe.x + TF.x, Fe.y + TF.y);
        op[2048 - l] = make_float2(Fe.x - TF.x, -(Fe.y - TF.y));   // conj(Fe - TF)
        float cn = c * c8 - s * s8;
        s = c * s8 + s * c8;
        c = cn;
    }
}

// irfft via inverse packing: Z[l] = Fe + i Fo rebuilt from U, then 2048 IFFT,
// y[2n]=Re(z), y[2n+1]=Im(z), scale 1/2048, exact GELU. float4 stores.
__global__ __launch_bounds__(256, 6) void irfft_gelu_k(const float2* __restrict__ Uhat,
                                                       float* __restrict__ out) {
    __shared__ __align__(16) float2 buf[FBUF];
    const int row = blockIdx.x;
    const int tid = threadIdx.x;
    const float2* wp = Uhat + (size_t)row * LF;
    float s, c;
    fsincos(3.14159265358979f * (float)tid / 2048.0f, &s, &c);
    const float c8 = 0.92387953251129f, s8 = 0.38268343236509f;   // exp(+i*pi/8)
    for (int l = tid; l < 1025; l += 256) {
        float2 Ul = wp[l];
        float2 Um = wp[2048 - l];
        float2 Fe = make_float2(0.5f * (Ul.x + Um.x), 0.5f * (Ul.y - Um.y));
        float2 Dv = make_float2(0.5f * (Ul.x - Um.x), 0.5f * (Ul.y + Um.y));
        float2 Fo = make_float2(Dv.x * c - Dv.y * s, Dv.x * s + Dv.y * c);
        buf[SKEW(l)] = make_float2(Fe.x - Fo.y, Fe.y + Fo.x);          // Fe + i Fo
        if (l >= 1 && l <= 1023)
            buf[SKEW(2048 - l)] = make_float2(Fe.x + Fo.y, Fo.x - Fe.y); // conj(Fe)+i conj(Fo)
        float cn = c * c8 - s * s8;
        s = c * s8 + s * c8;
        c = cn;
    }
    __syncthreads();
    fft2048_ip<1>(buf);
    float4* op4 = (float4*)(out + (size_t)row * Ln);
    #pragma unroll
    for (int r = 0; r < 4; ++r) {
        int n = 2 * (tid + (r << 8));
        float2 z0 = buf[SKEW(n)];
        float2 z1 = buf[SKEW(n + 1)];
        float y0 = z0.x * (1.0f / 2048.0f);
        float y1 = z0.y * (1.0f / 2048.0f);
        float y2 = z1.x * (1.0f / 2048.0f);
        float y3 = z1.y * (1.0f / 2048.0f);
        op4[tid + (r << 8)] = make_float4(
            0.5f * y0 * (1.0f + erff(y0 * 0.70710678118655f)),
            0.5f * y1 * (1.0f + erff(y1 * 0.70710678118655f)),
            0.5f * y2 * (1.0f + erff(y2 * 0.70710678118655f)),
            0.5f * y3 * (1.0f + erff(y3 * 0.70710678118655f)));
    }
}

// ---------------------------------------------------------------------------
// mixmm: NT=32 columns/block (unchanged from r7 — 59 -> ~sub-30 us).
// ---------------------------------------------------------------------------
__device__ __forceinline__ f32x4 mfma16h(f16x8 a, f16x8 b, f32x4 c) {
    return __builtin_amdgcn_mfma_f32_16x16x32_f16(a, b, c, 0, 0, 0);
}
__device__ __forceinline__ f16x8 read_frag(const _Float16* plane, int n, int k) {
    int ksw = k ^ ((n & 7) << 3);
    return *(const f16x8*)(plane + n * 128 + ksw);
}
__device__ __forceinline__ f16x8 aread(const _Float16* W, int pl, int m, int k) {
    return *(const f16x8*)(W + pl * WPLSZ + m * 128 + k);
}

__global__ __launch_bounds__(256, 4) void mixmm_k(float2* __restrict__ Uhat,
                                                  const _Float16* __restrict__ W1,
                                                  const _Float16* __restrict__ W2,
                                                  const _Float16* __restrict__ W3,
                                                  const float* __restrict__ Lam) {
    __shared__ __align__(16) _Float16 Up[2 * PLSZ];      // 16 KB  {r, i}
    __shared__ __align__(16) _Float16 Tp[2 * PLSZ];      // 16 KB  {r, i}

    const int tid = threadIdx.x;
    const int b = blockIdx.x / NTILES;
    const int tile = blockIdx.x % NTILES;
    const int l0 = tile * NT;
    const int ncols = (LF - l0) < NT ? (LF - l0) : NT;

    // ---- direct load U tile -> fp16 planes [n][k=h], XOR-swizzled ----
    {
        int n = tid & 31, kc = tid >> 5;
        float2 v[16];
        #pragma unroll
        for (int j = 0; j < 16; ++j) {
            int h = kc * 16 + j;
            v[j] = (n < ncols) ? Uhat[(size_t)(b * 128 + h) * LF + l0 + n]
                               : make_float2(0.f, 0.f);
        }
        #pragma unroll
        for (int jc = 0; jc < 2; ++jc) {
            f16x8 fr, fi;
            #pragma unroll
            for (int j = 0; j < 8; ++j) {
                fr[j] = (_Float16)v[jc * 8 + j].x;
                fi[j] = (_Float16)v[jc * 8 + j].y;
            }
            int ksw = (kc * 16 + jc * 8) ^ ((n & 7) << 3);
            *(f16x8*)(Up + 0 * PLSZ + n * 128 + ksw) = fr;
            *(f16x8*)(Up + 1 * PLSZ + n * 128 + ksw) = fi;
        }
    }
    __syncthreads();

    const int lane = tid & 63;
    const int w = tid >> 6;          // wave: m rows w*32 .. w*32+31
    const int m15 = lane & 15;
    const int quad = lane >> 4;

    f32x4 accR[2][2], accM[2][2], accI[2][2];   // [s][t]
    #pragma unroll
    for (int s = 0; s < 2; ++s)
        #pragma unroll
        for (int t = 0; t < 2; ++t) {
            accR[s][t] = (f32x4)0.f; accM[s][t] = (f32x4)0.f; accI[s][t] = (f32x4)0.f;
        }

    // ---- stage 1: T = B2 @ U ----
    #pragma unroll
    for (int kb = 0; kb < 4; ++kb) {
        int k = kb * 32 + quad * 8;
        f16x8 wr[2], wi[2];
        #pragma unroll
        for (int s = 0; s < 2; ++s) {
            int m = w * 32 + s * 16 + m15;
            wr[s] = aread(W1, 0, m, k);
            wi[s] = aread(W1, 1, m, k);
        }
        f16x8 br[2], bi[2];
        #pragma unroll
        for (int t = 0; t < 2; ++t) {
            br[t] = read_frag(Up + 0 * PLSZ, t * 16 + m15, k);
            bi[t] = read_frag(Up + 1 * PLSZ, t * 16 + m15, k);
        }
        #pragma unroll
        for (int s = 0; s < 2; ++s)
            #pragma unroll
            for (int t = 0; t < 2; ++t) {
                accR[s][t] = mfma16h(wr[s], br[t], accR[s][t]);
                accM[s][t] = mfma16h(wi[s], bi[t], accM[s][t]);
                accI[s][t] = mfma16h(wr[s], bi[t], accI[s][t]);
                accI[s][t] = mfma16h(wi[s], br[t], accI[s][t]);
            }
    }

    // ---- Cauchy scale (x 1/TSCALE) + write T planes ----
    #pragma unroll
    for (int s = 0; s < 2; ++s) {
        #pragma unroll
        for (int reg = 0; reg < 4; ++reg) {
            int p = w * 32 + s * 16 + quad * 4 + reg;
            float2 lamv = ((const float2*)Lam)[p];
            float dr = -lamv.x;
            #pragma unroll
            for (int t = 0; t < 2; ++t) {
                int n = t * 16 + m15;
                int l = l0 + n;
                float di = 3.14159265358979f * (float)l / 2048.0f - lamv.y;
                float inv = (1.0f / TSCALE) / (dr * dr + di * di);
                float xr = accR[s][t][reg] - accM[s][t][reg];
                float xi = accI[s][t][reg];
                float tr = (xr * dr + xi * di) * inv;
                float ti = (xi * dr - xr * di) * inv;
                int off = n * 128 + (p ^ ((n & 7) << 3));
                Tp[0 * PLSZ + off] = (_Float16)tr;
                Tp[1 * PLSZ + off] = (_Float16)ti;
            }
        }
    }
    __syncthreads();   // T planes visible

    // ---- stage 2: W = (64*C2) @ T + D2 @ U ----
    #pragma unroll
    for (int s = 0; s < 2; ++s)
        #pragma unroll
        for (int t = 0; t < 2; ++t) {
            accR[s][t] = (f32x4)0.f; accM[s][t] = (f32x4)0.f; accI[s][t] = (f32x4)0.f;
        }

    #pragma unroll
    for (int kb = 0; kb < 4; ++kb) {
        int k = kb * 32 + quad * 8;
        // -- C2 @ T --
        {
            f16x8 wr[2], wi[2];
            #pragma unroll
            for (int s = 0; s < 2; ++s) {
                int m = w * 32 + s * 16 + m15;
                wr[s] = aread(W2, 0, m, k);
                wi[s] = aread(W2, 1, m, k);
            }
            f16x8 br[2], bi[2];
            #pragma unroll
            for (int t = 0; t < 2; ++t) {
                br[t] = read_frag(Tp + 0 * PLSZ, t * 16 + m15, k);
                bi[t] = read_frag(Tp + 1 * PLSZ, t * 16 + m15, k);
            }
            #pragma unroll
            for (int s = 0; s < 2; ++s)
                #pragma unroll
                for (int t = 0; t < 2; ++t) {
                    accR[s][t] = mfma16h(wr[s], br[t], accR[s][t]);
                    accM[s][t] = mfma16h(wi[s], bi[t], accM[s][t]);
                    accI[s][t] = mfma16h(wr[s], bi[t], accI[s][t]);
                    accI[s][t] = mfma16h(wi[s], br[t], accI[s][t]);
                }
        }
        // -- D2 @ U --
        {
            f16x8 wr[2], wi[2];
            #pragma unroll
            for (int s = 0; s < 2; ++s) {
                int m = w * 32 + s * 16 + m15;
                wr[s] = aread(W3, 0, m, k);
                wi[s] = aread(W3, 1, m, k);
            }
            f16x8 br[2], bi[2];
            #pragma unroll
            for (int t = 0; t < 2; ++t) {
                br[t] = read_frag(Up + 0 * PLSZ, t * 16 + m15, k);
                bi[t] = read_frag(Up + 1 * PLSZ, t * 16 + m15, k);
            }
            #pragma unroll
            for (int s = 0; s < 2; ++s)
                #pragma unroll
                for (int t = 0; t < 2; ++t) {
                    accR[s][t] = mfma16h(wr[s], br[t], accR[s][t]);
                    accM[s][t] = mfma16h(wi[s], bi[t], accM[s][t]);
                    accI[s][t] = mfma16h(wr[s], bi[t], accI[s][t]);
                    accI[s][t] = mfma16h(wi[s], br[t], accI[s][t]);
                }
        }
    }

    // ---- write W back to Uhat (block-disjoint tiles) ----
    #pragma unroll
    for (int s = 0; s < 2; ++s) {
        #pragma unroll
        for (int t = 0; t < 2; ++t) {
            int n = t * 16 + m15;
            if (n < ncols) {
                #pragma unroll
                for (int reg = 0; reg < 4; ++reg) {
                    int m = w * 32 + s * 16 + quad * 4 + reg;
                    Uhat[(size_t)(b * 128 + m) * LF + l0 + n] =
                        make_float2(accR[s][t][reg] - accM[s][t][reg], accI[s][t][reg]);
                }
            }
        }
    }
}

// ---------------------------------------------------------------------------
extern "C" void kernel_launch(void* const* d_in, const int* in_sizes, int n_in,
                              void* d_out, int out_size, void* d_ws, size_t ws_size,
                              hipStream_t stream) {
    const float* u    = (const float*)d_in[0];   // (B,H,L)
    const float* C_ri = (const float*)d_in[1];   // (H,P,2)
    const float* D_ri = (const float*)d_in[2];   // (H,H,2)
    const float* B_ri = (const float*)d_in[3];   // (P,H,2)
    const float* Lam  = (const float*)d_in[4];   // (P,2)
    float* out = (float*)d_out;

    float2* Uhat = (float2*)d_ws;                          // 1024*2049 float2 = 16 MiB
    _Float16* W1 = (_Float16*)(Uhat + (size_t)NROWS * LF);
    _Float16* W2 = W1 + 2 * WPLSZ;
    _Float16* W3 = W2 + 2 * WPLSZ;
    float2* Em = (float2*)(W3 + 2 * WPLSZ);

    prep_ABE_k<<<192, 256, 0, stream>>>(B_ri, C_ri, D_ri, W1, W2, Em);
    prep_W3_k<<<64, 256, 0, stream>>>(Em, W3);

    rfft_rows_k<<<NROWS, 256, 0, stream>>>(u, Uhat);
    mixmm_k<<<Bn * NTILES, 256, 0, stream>>>(Uhat, W1, W2, W3, Lam);
    irfft_gelu_k<<<NROWS, 256, 0, stream>>>(Uhat, out);
}